// Round 10
// baseline (239.446 us; speedup 1.0000x reference)
//
#include <hip/hip_runtime.h>

typedef short  s16x8 __attribute__((ext_vector_type(8)));   // 8 bf16 bit patterns
typedef float  f32x4 __attribute__((ext_vector_type(4)));
typedef unsigned int u32;
typedef unsigned int u32x4 __attribute__((ext_vector_type(4)));
typedef unsigned short u16;

#define DEVI static __device__ __forceinline__

constexpr int T_  = 128;
constexpr int F_  = 14;
constexpr int H_  = 64;
constexpr int BPB = 16;   // batch rows per block

DEVI u16 f2bf(float f) {                     // RNE, one-time weight convert
  u32 u = __builtin_bit_cast(u32, f);
  u += 0x7fffu + ((u >> 16) & 1u);
  return (u16)(u >> 16);
}
DEVI u16 f2bfF(float f) {                    // round-half-up (x / h in-loop path)
  u32 u = __builtin_bit_cast(u32, f);
  return (u16)((u + 0x8000u) >> 16);
}
DEVI u32 pkbf(float a, float b) {            // pack 2 bf16 into one dword
  u32 ua = __builtin_bit_cast(u32, a) + 0x8000u;
  u32 ub = __builtin_bit_cast(u32, b) + 0x8000u;
  return (ua >> 16) | (ub & 0xffff0000u);
}
// B-frag kt from tanh'd acc tiles: elements 0-3 = tile kt, 4-7 = tile kt+2
DEVI s16x8 packfrag(const f32x4& a, const f32x4& b) {
  u32x4 p;
  p[0] = pkbf(a[0], a[1]); p[1] = pkbf(a[2], a[3]);
  p[2] = pkbf(b[0], b[1]); p[3] = pkbf(b[2], b[3]);
  return __builtin_bit_cast(s16x8, p);
}
DEVI float tanhfast(float x) {
  float e = exp2f(x * -2.8853900817779268f);
  float r = __builtin_amdgcn_rcpf(1.0f + e);
  return __builtin_fmaf(2.0f, r, -1.0f);
}
DEVI f32x4 tanh4(const f32x4& v) {
  f32x4 r;
  r[0] = tanhfast(v[0]); r[1] = tanhfast(v[1]);
  r[2] = tanhfast(v[2]); r[3] = tanhfast(v[3]);
  return r;
}
DEVI f32x4 MFMA(s16x8 a, s16x8 b, f32x4 c) {
  return __builtin_amdgcn_mfma_f32_16x16x32_bf16(a, b, c, 0, 0, 0);
}
DEVI s16x8 ldrow8(const float* p) {          // 8 contiguous fp32 -> bf16 A-frag
  const f32x4 a = ((const f32x4*)p)[0];
  const f32x4 b = ((const f32x4*)p)[1];
  s16x8 r;
  r[0] = (short)f2bf(a[0]); r[1] = (short)f2bf(a[1]);
  r[2] = (short)f2bf(a[2]); r[3] = (short)f2bf(a[3]);
  r[4] = (short)f2bf(b[0]); r[5] = (short)f2bf(b[1]);
  r[6] = (short)f2bf(b[2]); r[7] = (short)f2bf(b[3]);
  return r;
}

// 3 waves/block; wave w owns layer w FULLY (R5/R8/R9-proven math + layouts).
// This round combines the two proven structural wins that were never together:
//  (1) x fully staged to LDS bf16 (R5-proven preload): ZERO global memory ops
//      in the T-loop, so the single barrier's forced vmcnt(0) drain is free.
//  (2) double-buffered handoff, ONE barrier per epoch (R8-proven protocol).
//  (3) parallel p/q MFMA trees (R9-proven, absmax-neutral).
//  (4) wave0's x-frag register-prefetched one step ahead (LDS latency hidden).
// Arithmetic path bit-identical to R8/R9 => absmax must be 5.859375e-3.
__global__ __launch_bounds__(192, 1) void rnn_h1(
    const float* __restrict__ x,
    const float* __restrict__ Wih0, const float* __restrict__ Whh0,
    const float* __restrict__ bih0, const float* __restrict__ bhh0,
    const float* __restrict__ Wih1, const float* __restrict__ Whh1,
    const float* __restrict__ bih1, const float* __restrict__ bhh1,
    const float* __restrict__ Wih2, const float* __restrict__ Whh2,
    const float* __restrict__ bih2, const float* __restrict__ bhh2,
    const float* __restrict__ fc1w, const float* __restrict__ fc1b,
    const float* __restrict__ fc2w, const float* __restrict__ fc2b,
    float* __restrict__ out)
{
  __shared__ __align__(16) u16   xl[T_][BPB][F_];   // 57344 B, x tile as bf16
  __shared__ __align__(16) u32x4 hX[2][2][2][64];   // 8192 B [buf][layer01][frag][lane]
  // fc-head unpermute scratch overlays dead xl after the loop (R5-proven).

  const int tid  = threadIdx.x;
  const int w    = tid >> 6;        // wave id = layer id
  const int lane = tid & 63;
  const int g    = lane >> 4;
  const int m    = lane & 15;
  const int b0   = blockIdx.x * BPB;

  // ---- preload x -> LDS bf16 (R5-verbatim: coalesced 4B loads, batched) ----
  {
    constexpr int NX = BPB * T_ * F_;     // 28672
    u16* xf = &xl[0][0][0];
    #pragma unroll 1
    for (int i0 = tid; i0 < NX; i0 += 192 * 8) {
      float v[8]; int off[8]; bool ok[8];
      #pragma unroll
      for (int q8 = 0; q8 < 8; q8++) {
        int i = i0 + 192 * q8;
        ok[q8] = (i < NX);
        if (!ok[q8]) i = NX - 1;
        const int mm = i / (T_ * F_), q = i - mm * (T_ * F_);
        const int tt = q / F_, kk = q - tt * F_;
        off[q8] = tt * (BPB * F_) + mm * F_ + kk;
        v[q8] = x[(size_t)(b0 + mm) * (T_ * F_) + q];
      }
      #pragma unroll
      for (int q8 = 0; q8 < 8; q8++) if (ok[q8]) xf[off[q8]] = f2bfF(v[q8]);
    }
  }
  // ---- zero handoff buffers (both bufs read before first writes) ----
  {
    u32x4 z; z[0] = 0; z[1] = 0; z[2] = 0; z[3] = 0;
    u32x4* hp = &hX[0][0][0][0];
    #pragma unroll 1
    for (int i = tid; i < 2 * 2 * 2 * 64; i += 192) hp[i] = z;
  }

  // ---- per-wave (per-layer) weights, all register-resident (R8-verbatim) ----
  s16x8 Ax[4], Ai[4][2], Ah[4][2];
  f32x4 bc[4];
  {
    const float* Wi = Wih1; const float* Wh = Whh0;
    const float* bi = bih0; const float* bh = bhh0;
    if (w == 1)      { Wi = Wih1; Wh = Whh1; bi = bih1; bh = bhh1; }
    else if (w == 2) { Wi = Wih2; Wh = Whh2; bi = bih2; bh = bhh2; }
    #pragma unroll
    for (int n = 0; n < 4; n++) {
      const int Lr = 32 * (n & 1) + 8 * (m >> 2) + 4 * (n >> 1) + (m & 3);
      if (w == 0) {                      // input side 64x14, zero-pad K to 32
        s16x8 r;
        #pragma unroll
        for (int j2 = 0; j2 < 8; j2++) {
          const int kk = 8 * g + j2;
          r[j2] = (kk < F_) ? (short)f2bf(Wih0[Lr * F_ + kk]) : (short)0;
        }
        Ax[n] = r;
        Ai[n][0] = r; Ai[n][1] = r;      // dead in wave0
      } else {
        #pragma unroll
        for (int kt = 0; kt < 2; kt++)
          Ai[n][kt] = ldrow8(Wi + Lr * H_ + 32 * kt + 8 * g);
        Ax[n] = Ai[n][0];                // dead in waves 1/2
      }
      #pragma unroll
      for (int kt = 0; kt < 2; kt++)
        Ah[n][kt] = ldrow8(Wh + Lr * H_ + 32 * kt + 8 * g);
      const int Lb = 32 * (n & 1) + 8 * g + 4 * (n >> 1);
      bc[n] = *(const f32x4*)(bi + Lb) + *(const f32x4*)(bh + Lb);
    }
  }

  // ---- hh-state frags (own layer), zero init ----
  s16x8 F[2];
  {
    s16x8 z;
    #pragma unroll
    for (int i = 0; i < 8; i++) z[i] = 0;
    F[0] = z; F[1] = z;
  }
  f32x4 z4; z4[0] = 0.f; z4[1] = 0.f; z4[2] = 0.f; z4[3] = 0.f;
  f32x4 h2v[4];
  #pragma unroll
  for (int n = 0; n < 4; n++) h2v[n] = z4;

  __syncthreads();   // xl + hX zeros visible

  // wave0 x-frag reader from LDS (R5-proven access pattern)
  auto ldx = [&](int t) -> s16x8 {
    u32 x0 = 0, x1 = 0, x2 = 0, x3 = 0;
    const u32* bp = (const u32*)&xl[t][m][0];   // 4B-aligned (28B row)
    if (g == 0)      { x0 = bp[0]; x1 = bp[1]; x2 = bp[2]; x3 = bp[3]; }
    else if (g == 1) { x0 = bp[4]; x1 = bp[5]; x2 = bp[6]; }
    u32x4 xv; xv[0] = x0; xv[1] = x1; xv[2] = x2; xv[3] = x3;
    return __builtin_bit_cast(s16x8, xv);
  };

  s16x8 bx, bxn;
  if (w == 0) bx = ldx(0);   // frag for t=0 (prefetch chain start)

  // ---- pipelined T-loop: ONE barrier per epoch (R8 dbuf protocol) ----
  #pragma unroll 1
  for (int e = 0; e < T_ + 2; e++) {
    const int t  = e - w;
    const int wb = e & 1, rb = wb ^ 1;

    // issue next-step x read immediately (latency hidden under p-tree MFMAs)
    if (w == 0) { int tn = e + 1; if (tn > T_ - 1) tn = T_ - 1; bxn = ldx(tn); }

    // read prev-layer frags from the buffer written LAST epoch (first DS ops)
    s16x8 Fp0, Fp1;
    if (w == 1) {
      Fp0 = __builtin_bit_cast(s16x8, hX[rb][0][0][lane]);
      Fp1 = __builtin_bit_cast(s16x8, hX[rb][0][1][lane]);
    } else if (w == 2) {
      Fp0 = __builtin_bit_cast(s16x8, hX[rb][1][0][lane]);
      Fp1 = __builtin_bit_cast(s16x8, hX[rb][1][1][lane]);
    } else {
      Fp0 = bx; Fp1 = bx;                // wave0: input already in registers
    }

    if (t >= 0 && t < T_) {              // wave-uniform
      f32x4 p[4], q[4], hv[4];
      // parallel trees (R9-proven): p = bc + Ah*F (register operands, issue
      // first to cover Fp ds_read latency); q = Ai*Fp into zero-C.
      #pragma unroll
      for (int n = 0; n < 4; n++) p[n] = MFMA(Ah[n][0], F[0], bc[n]);
      #pragma unroll
      for (int n = 0; n < 4; n++) p[n] = MFMA(Ah[n][1], F[1], p[n]);
      if (w == 0) {
        #pragma unroll
        for (int n = 0; n < 4; n++) q[n] = MFMA(Ax[n], Fp0, z4);
      } else {
        #pragma unroll
        for (int n = 0; n < 4; n++) q[n] = MFMA(Ai[n][0], Fp0, z4);
        #pragma unroll
        for (int n = 0; n < 4; n++) q[n] = MFMA(Ai[n][1], Fp1, q[n]);
      }
      #pragma unroll
      for (int n = 0; n < 4; n++) hv[n] = tanh4(p[n] + q[n]);
      F[0] = packfrag(hv[0], hv[2]);
      F[1] = packfrag(hv[1], hv[3]);
      if (w == 0) {
        hX[wb][0][0][lane] = __builtin_bit_cast(u32x4, F[0]);
        hX[wb][0][1][lane] = __builtin_bit_cast(u32x4, F[1]);
      } else if (w == 1) {
        hX[wb][1][0][lane] = __builtin_bit_cast(u32x4, F[0]);
        hX[wb][1][1][lane] = __builtin_bit_cast(u32x4, F[1]);
      } else if (t == T_ - 1) {
        #pragma unroll
        for (int n = 0; n < 4; n++) h2v[n] = hv[n];   // fp32 h2 for head
      }
    }

    if (w == 0) bx = bxn;                // rotate x prefetch
    __syncthreads();   // single END barrier (no global ops in flight -> cheap)
  }

  // ---- FC head: wave 2 un-permutes fp32 h2 into dead xl; wave 0 computes ----
  float (*h2l)[68] = (float (*)[68])&xl[0][0][0];
  if (w == 2) {
    #pragma unroll
    for (int n = 0; n < 4; n++) {
      const int Lb = 32 * (n & 1) + 8 * g + 4 * (n >> 1);
      *(f32x4*)&h2l[m][Lb] = h2v[n];
    }
  }
  __syncthreads();

  if (w == 0) {
    float hr[64];
    #pragma unroll
    for (int q = 0; q < 16; q++) {
      f32x4 v = *(const f32x4*)&h2l[m][4 * q];
      hr[4 * q + 0] = v[0]; hr[4 * q + 1] = v[1];
      hr[4 * q + 2] = v[2]; hr[4 * q + 3] = v[3];
    }
    float acc2 = 0.f;
    #pragma unroll
    for (int jj = 0; jj < 8; jj++) {
      const int jf = 8 * g + jj;
      float s = fc1b[jf];
      const f32x4* wp = (const f32x4*)(fc1w + jf * H_);
      #pragma unroll
      for (int kq = 0; kq < 16; kq++) {
        f32x4 wv = wp[kq];
        s += hr[4 * kq + 0] * wv[0] + hr[4 * kq + 1] * wv[1]
           + hr[4 * kq + 2] * wv[2] + hr[4 * kq + 3] * wv[3];
      }
      s = fmaxf(s, 0.f);
      acc2 += s * fc2w[jf];
    }
    acc2 += __shfl_xor(acc2, 16, 64);
    acc2 += __shfl_xor(acc2, 32, 64);
    if (lane < 16) out[b0 + m] = acc2 + fc2b[0];
  }
}

extern "C" void kernel_launch(void* const* d_in, const int* in_sizes, int n_in,
                              void* d_out, int out_size, void* d_ws, size_t ws_size,
                              hipStream_t stream) {
  const float* x    = (const float*)d_in[0];
  const float* Wih0 = (const float*)d_in[1];
  const float* Whh0 = (const float*)d_in[2];
  const float* bih0 = (const float*)d_in[3];
  const float* bhh0 = (const float*)d_in[4];
  const float* Wih1 = (const float*)d_in[5];
  const float* Whh1 = (const float*)d_in[6];
  const float* bih1 = (const float*)d_in[7];
  const float* bhh1 = (const float*)d_in[8];
  const float* Wih2 = (const float*)d_in[9];
  const float* Whh2 = (const float*)d_in[10];
  const float* bih2 = (const float*)d_in[11];
  const float* bhh2 = (const float*)d_in[12];
  const float* fc1w = (const float*)d_in[13];
  const float* fc1b = (const float*)d_in[14];
  const float* fc2w = (const float*)d_in[15];
  const float* fc2b = (const float*)d_in[16];

  rnn_h1<<<dim3(4096 / BPB), dim3(192), 0, stream>>>(
      x, Wih0, Whh0, bih0, bhh0, Wih1, Whh1, bih1, bhh1,
      Wih2, Whh2, bih2, bhh2, fc1w, fc1b, fc2w, fc2b, (float*)d_out);
}

// Round 11
// 199.002 us; speedup vs baseline: 1.2032x; 1.2032x over previous
//
#include <hip/hip_runtime.h>

typedef short  s16x8 __attribute__((ext_vector_type(8)));   // 8 bf16 bit patterns
typedef float  f32x4 __attribute__((ext_vector_type(4)));
typedef float  f32x2 __attribute__((ext_vector_type(2)));
typedef unsigned int u32;
typedef unsigned int u32x4 __attribute__((ext_vector_type(4)));
typedef unsigned short u16;

#define DEVI static __device__ __forceinline__

#if __has_builtin(__builtin_amdgcn_exp2f)
#define EXP2(v) __builtin_amdgcn_exp2f(v)   // raw v_exp_f32, no libm fixup code
#else
#define EXP2(v) exp2f(v)
#endif

constexpr int T_  = 128;
constexpr int F_  = 14;
constexpr int H_  = 64;
constexpr int BPB = 16;   // batch rows per block

DEVI u16 f2bf(float f) {                     // RNE, one-time weight convert
  u32 u = __builtin_bit_cast(u32, f);
  u += 0x7fffu + ((u >> 16) & 1u);
  return (u16)(u >> 16);
}
DEVI u16 f2bfF(float f) {                    // round-half-up (x / h in-loop path)
  u32 u = __builtin_bit_cast(u32, f);
  return (u16)((u + 0x8000u) >> 16);
}
DEVI u32 pkbf(float a, float b) {            // pack 2 bf16 into one dword
  u32 ua = __builtin_bit_cast(u32, a) + 0x8000u;
  u32 ub = __builtin_bit_cast(u32, b) + 0x8000u;
  return (ua >> 16) | (ub & 0xffff0000u);
}
// B-frag kt from tanh'd acc tiles: elements 0-3 = tile kt, 4-7 = tile kt+2
DEVI s16x8 packfrag(const f32x4& a, const f32x4& b) {
  u32x4 p;
  p[0] = pkbf(a[0], a[1]); p[1] = pkbf(a[2], a[3]);
  p[2] = pkbf(b[0], b[1]); p[3] = pkbf(b[2], b[3]);
  return __builtin_bit_cast(s16x8, p);
}
DEVI float tanhfast(float x) {               // 5 instrs with raw exp2
  float e = EXP2(x * -2.8853900817779268f);
  float r = __builtin_amdgcn_rcpf(1.0f + e);
  return __builtin_fmaf(2.0f, r, -1.0f);
}
DEVI f32x4 tanh4(const f32x4& v) {
  f32x4 r;
  r[0] = tanhfast(v[0]); r[1] = tanhfast(v[1]);
  r[2] = tanhfast(v[2]); r[3] = tanhfast(v[3]);
  return r;
}
DEVI f32x4 MFMA(s16x8 a, s16x8 b, f32x4 c) {
  return __builtin_amdgcn_mfma_f32_16x16x32_bf16(a, b, c, 0, 0, 0);
}
DEVI s16x8 ldrow8(const float* p) {          // 8 contiguous fp32 -> bf16 A-frag
  const f32x4 a = ((const f32x4*)p)[0];
  const f32x4 b = ((const f32x4*)p)[1];
  s16x8 r;
  r[0] = (short)f2bf(a[0]); r[1] = (short)f2bf(a[1]);
  r[2] = (short)f2bf(a[2]); r[3] = (short)f2bf(a[3]);
  r[4] = (short)f2bf(b[0]); r[5] = (short)f2bf(b[1]);
  r[6] = (short)f2bf(b[2]); r[7] = (short)f2bf(b[3]);
  return r;
}

// 6 waves/block: wave w -> (layer l = w>>1, role = w&1). Role A (0) computes the
// input tree q(l,t) = Wih_l * h_{l-1}(t); role B (1) owns the recurrence:
// hv = tanh(q + bc + Whh_l * h_l(t-1)), packs bf16 frags (R5/R8-proven repack),
// publishes them for layer l+1's A-wave. The q handoff is SAME-LANE C-layout
// f32x4 -> f32x4 (no layout algebra), double-buffered by epoch parity, so the
// R8-proven single-barrier protocol carries over unchanged.
// Schedule: epoch e: waveA(l) does t=e-2l; waveB(l) does t=e-2l-1.
//   waveA(l>=1) reads hf[par(e-1)][l-1] (written by waveB(l-1) at e-1);
//   waveB(l) reads q[par(e-1)][l]       (written by waveA(l)   at e-1).
// Arithmetic path bit-identical to R9/R10 => absmax must be 5.859375e-3.
__global__ __launch_bounds__(384, 1) void rnn_ab(
    const float* __restrict__ x,
    const float* __restrict__ Wih0, const float* __restrict__ Whh0,
    const float* __restrict__ bih0, const float* __restrict__ bhh0,
    const float* __restrict__ Wih1, const float* __restrict__ Whh1,
    const float* __restrict__ bih1, const float* __restrict__ bhh1,
    const float* __restrict__ Wih2, const float* __restrict__ Whh2,
    const float* __restrict__ bih2, const float* __restrict__ bhh2,
    const float* __restrict__ fc1w, const float* __restrict__ fc1b,
    const float* __restrict__ fc2w, const float* __restrict__ fc2b,
    float* __restrict__ out)
{
  __shared__ __align__(16) u32x4 hf[2][2][2][64];   // [par][layer01][frag][lane] 8 KiB
  __shared__ __align__(16) f32x4 qb[2][3][4][64];   // [par][layer][n][lane]    24 KiB
  __shared__ __align__(16) float h2l[BPB][68];      // fc-head unpermute scratch

  const int tid  = threadIdx.x;
  const int w    = tid >> 6;
  const int lane = tid & 63;
  const int g    = lane >> 4;
  const int m    = lane & 15;
  const int l    = w >> 1;          // layer
  const int role = w & 1;           // 0 = A (input tree), 1 = B (recurrence)
  const int b0   = blockIdx.x * BPB;

  f32x4 z4; z4[0] = 0.f; z4[1] = 0.f; z4[2] = 0.f; z4[3] = 0.f;

  // ---- zero handoff buffers (defensive; active reads always hit written slots)
  {
    u32x4 z; z[0] = 0; z[1] = 0; z[2] = 0; z[3] = 0;
    u32x4* hp = &hf[0][0][0][0];
    #pragma unroll 1
    for (int i = tid; i < 2 * 2 * 2 * 64; i += 384) hp[i] = z;
    f32x4* qp = &qb[0][0][0][0];
    #pragma unroll 1
    for (int i = tid; i < 2 * 3 * 4 * 64; i += 384) qp[i] = z4;
  }

  // ---- per-wave role weights (register-resident) ----
  // role A: Wf = Wih_l A-frags (l=0: 64x14 zero-padded, single frag per n)
  // role B: Wf = Whh_l A-frags, bc = bih_l + bhh_l (C-layout f32x4 per n)
  s16x8 Wf[4][2];
  f32x4 bc[4];
  {
    const float* Wsrc;
    const float* bi = bih0; const float* bh = bhh0;
    if (role == 1) {
      Wsrc = (l == 0) ? Whh0 : (l == 1) ? Whh1 : Whh2;
      bi   = (l == 0) ? bih0 : (l == 1) ? bih1 : bih2;
      bh   = (l == 0) ? bhh0 : (l == 1) ? bhh1 : bhh2;
    } else {
      Wsrc = (l == 0) ? Wih0 : (l == 1) ? Wih1 : Wih2;
    }
    #pragma unroll
    for (int n = 0; n < 4; n++) {
      const int Lr = 32 * (n & 1) + 8 * (m >> 2) + 4 * (n >> 1) + (m & 3);
      if (role == 0 && l == 0) {         // input side 64x14, zero-pad K to 32
        s16x8 r;
        #pragma unroll
        for (int j2 = 0; j2 < 8; j2++) {
          const int kk = 8 * g + j2;
          r[j2] = (kk < F_) ? (short)f2bf(Wih0[Lr * F_ + kk]) : (short)0;
        }
        Wf[n][0] = r; Wf[n][1] = r;
      } else {
        #pragma unroll
        for (int kt = 0; kt < 2; kt++)
          Wf[n][kt] = ldrow8(Wsrc + Lr * H_ + 32 * kt + 8 * g);
      }
      if (role == 1) {
        const int Lb = 32 * (n & 1) + 8 * g + 4 * (n >> 1);
        bc[n] = *(const f32x4*)(bi + Lb) + *(const f32x4*)(bh + Lb);
      } else {
        bc[n] = z4;
      }
    }
  }

  // ---- role-B hh-state frags, zero init ----
  s16x8 F[2];
  {
    s16x8 z;
    #pragma unroll
    for (int i = 0; i < 8; i++) z[i] = 0;
    F[0] = z; F[1] = z;
  }
  f32x4 h2v[4];
  #pragma unroll
  for (int n = 0; n < 4; n++) h2v[n] = z4;

  // ---- waveA(0) x pipeline: global float2 loads, distance-3 (R8-verbatim) ----
  const float* xrow = x + (size_t)(b0 + m) * T_ * F_;
  auto ldraw = [&](int t, f32x4& ra, f32x4& rb) {
    const float* p = xrow + t * F_;
    if (g == 0) {
      f32x2 p0 = *(const f32x2*)(p),     p1 = *(const f32x2*)(p + 2);
      f32x2 p2 = *(const f32x2*)(p + 4), p3 = *(const f32x2*)(p + 6);
      ra[0] = p0[0]; ra[1] = p0[1]; ra[2] = p1[0]; ra[3] = p1[1];
      rb[0] = p2[0]; rb[1] = p2[1]; rb[2] = p3[0]; rb[3] = p3[1];
    } else if (g == 1) {
      f32x2 p4 = *(const f32x2*)(p + 8), p5 = *(const f32x2*)(p + 10);
      f32x2 p6 = *(const f32x2*)(p + 12);
      ra[0] = p4[0]; ra[1] = p4[1]; ra[2] = p5[0]; ra[3] = p5[1];
      rb[0] = p6[0]; rb[1] = p6[1]; rb[2] = 0.f;   rb[3] = 0.f;
    } else {
      ra = z4; rb = z4;
    }
  };
  auto cvtraw = [&](const f32x4& ra, const f32x4& rb) -> s16x8 {
    s16x8 r;
    r[0] = (short)f2bfF(ra[0]); r[1] = (short)f2bfF(ra[1]);
    r[2] = (short)f2bfF(ra[2]); r[3] = (short)f2bfF(ra[3]);
    r[4] = (short)f2bfF(rb[0]); r[5] = (short)f2bfF(rb[1]);
    r[6] = (short)f2bfF(rb[2]); r[7] = (short)f2bfF(rb[3]);
    return r;
  };
  s16x8 bx;
  f32x4 Ba0, Ba1, Ca0, Ca1, Da0, Da1;
  const bool isX = (role == 0) && (l == 0);
  if (isX) {
    f32x4 t0, t1;
    ldraw(0, t0, t1); bx = cvtraw(t0, t1);
    ldraw(1, Ba0, Ba1);
    ldraw(2, Ca0, Ca1);
  }

  __syncthreads();   // LDS zeros visible

  // ---- pipelined T-loop: ONE barrier per epoch (R8 dbuf protocol) ----
  #pragma unroll 1
  for (int e = 0; e < T_ + 5; e++) {
    const int par = e & 1, rp = par ^ 1;

    if (role == 0) {
      // ============ role A: input tree ============
      const int t = e - 2 * l;
      if (isX) { int tp = e + 3; if (tp > T_ - 1) tp = T_ - 1; ldraw(tp, Da0, Da1); }
      s16x8 Fp0, Fp1;
      if (l == 0) {
        Fp0 = bx; Fp1 = bx;
      } else {
        Fp0 = __builtin_bit_cast(s16x8, hf[rp][l - 1][0][lane]);
        Fp1 = __builtin_bit_cast(s16x8, hf[rp][l - 1][1][lane]);
      }
      if (t >= 0 && t < T_) {
        f32x4 q[4];
        #pragma unroll
        for (int n = 0; n < 4; n++) q[n] = MFMA(Wf[n][0], Fp0, z4);
        if (l != 0) {
          #pragma unroll
          for (int n = 0; n < 4; n++) q[n] = MFMA(Wf[n][1], Fp1, q[n]);
        }
        #pragma unroll
        for (int n = 0; n < 4; n++) qb[par][l][n][lane] = q[n];
      }
      if (isX) {
        bx = cvtraw(Ba0, Ba1);
        Ba0 = Ca0; Ba1 = Ca1; Ca0 = Da0; Ca1 = Da1;
      }
    } else {
      // ============ role B: recurrence ============
      const int t = e - 2 * l - 1;
      if (t >= 0 && t < T_) {
        f32x4 p[4], hv[4];
        // register-operand hh-MFMAs first: cover the q ds_read latency
        #pragma unroll
        for (int n = 0; n < 4; n++) p[n] = MFMA(Wf[n][0], F[0], bc[n]);
        #pragma unroll
        for (int n = 0; n < 4; n++) p[n] = MFMA(Wf[n][1], F[1], p[n]);
        f32x4 q0 = qb[rp][l][0][lane];
        f32x4 q1 = qb[rp][l][1][lane];
        f32x4 q2 = qb[rp][l][2][lane];
        f32x4 q3 = qb[rp][l][3][lane];
        hv[0] = tanh4(p[0] + q0);
        hv[1] = tanh4(p[1] + q1);
        hv[2] = tanh4(p[2] + q2);
        hv[3] = tanh4(p[3] + q3);
        F[0] = packfrag(hv[0], hv[2]);
        F[1] = packfrag(hv[1], hv[3]);
        if (l < 2) {
          hf[par][l][0][lane] = __builtin_bit_cast(u32x4, F[0]);
          hf[par][l][1][lane] = __builtin_bit_cast(u32x4, F[1]);
        } else if (t == T_ - 1) {
          #pragma unroll
          for (int n = 0; n < 4; n++) h2v[n] = hv[n];   // fp32 h2 for head
        }
      }
    }
    __syncthreads();   // single END barrier (R8-proven dbuf ordering)
  }

  // ---- FC head: waveB(2) un-permutes fp32 h2; wave 0 computes (proven) ----
  if (role == 1 && l == 2) {
    #pragma unroll
    for (int n = 0; n < 4; n++) {
      const int Lb = 32 * (n & 1) + 8 * g + 4 * (n >> 1);
      *(f32x4*)&h2l[m][Lb] = h2v[n];
    }
  }
  __syncthreads();

  if (w == 0) {
    float hr[64];
    #pragma unroll
    for (int q = 0; q < 16; q++) {
      f32x4 v = *(const f32x4*)&h2l[m][4 * q];
      hr[4 * q + 0] = v[0]; hr[4 * q + 1] = v[1];
      hr[4 * q + 2] = v[2]; hr[4 * q + 3] = v[3];
    }
    float acc2 = 0.f;
    #pragma unroll
    for (int jj = 0; jj < 8; jj++) {
      const int jf = 8 * g + jj;
      float s = fc1b[jf];
      const f32x4* wp = (const f32x4*)(fc1w + jf * H_);
      #pragma unroll
      for (int kq = 0; kq < 16; kq++) {
        f32x4 wv = wp[kq];
        s += hr[4 * kq + 0] * wv[0] + hr[4 * kq + 1] * wv[1]
           + hr[4 * kq + 2] * wv[2] + hr[4 * kq + 3] * wv[3];
      }
      s = fmaxf(s, 0.f);
      acc2 += s * fc2w[jf];
    }
    acc2 += __shfl_xor(acc2, 16, 64);
    acc2 += __shfl_xor(acc2, 32, 64);
    if (lane < 16) out[b0 + m] = acc2 + fc2b[0];
  }
}

extern "C" void kernel_launch(void* const* d_in, const int* in_sizes, int n_in,
                              void* d_out, int out_size, void* d_ws, size_t ws_size,
                              hipStream_t stream) {
  const float* x    = (const float*)d_in[0];
  const float* Wih0 = (const float*)d_in[1];
  const float* Whh0 = (const float*)d_in[2];
  const float* bih0 = (const float*)d_in[3];
  const float* bhh0 = (const float*)d_in[4];
  const float* Wih1 = (const float*)d_in[5];
  const float* Whh1 = (const float*)d_in[6];
  const float* bih1 = (const float*)d_in[7];
  const float* bhh1 = (const float*)d_in[8];
  const float* Wih2 = (const float*)d_in[9];
  const float* Whh2 = (const float*)d_in[10];
  const float* bih2 = (const float*)d_in[11];
  const float* bhh2 = (const float*)d_in[12];
  const float* fc1w = (const float*)d_in[13];
  const float* fc1b = (const float*)d_in[14];
  const float* fc2w = (const float*)d_in[15];
  const float* fc2b = (const float*)d_in[16];

  rnn_ab<<<dim3(4096 / BPB), dim3(384), 0, stream>>>(
      x, Wih0, Whh0, bih0, bhh0, Wih1, Whh1, bih1, bhh1,
      Wih2, Whh2, bih2, bhh2, fc1w, fc1b, fc2w, fc2b, (float*)d_out);
}

// Round 12
// 191.845 us; speedup vs baseline: 1.2481x; 1.0373x over previous
//
#include <hip/hip_runtime.h>

typedef short  s16x8 __attribute__((ext_vector_type(8)));   // 8 bf16 bit patterns
typedef float  f32x4 __attribute__((ext_vector_type(4)));
typedef float  f32x2 __attribute__((ext_vector_type(2)));
typedef unsigned int u32;
typedef unsigned int u32x4 __attribute__((ext_vector_type(4)));
typedef unsigned short u16;

#define DEVI static __device__ __forceinline__

#if __has_builtin(__builtin_amdgcn_exp2f)
#define EXP2(v) __builtin_amdgcn_exp2f(v)   // raw v_exp_f32 (R11-proven)
#else
#define EXP2(v) exp2f(v)
#endif

constexpr int T_  = 128;
constexpr int F_  = 14;
constexpr int H_  = 64;
constexpr int BPB = 16;   // batch rows per block
constexpr int K_  = 8;    // timesteps per epoch (chunk)
constexpr int NCH = T_ / K_;   // 16 chunks

DEVI u16 f2bf(float f) {                     // RNE, one-time weight convert
  u32 u = __builtin_bit_cast(u32, f);
  u += 0x7fffu + ((u >> 16) & 1u);
  return (u16)(u >> 16);
}
DEVI u16 f2bfF(float f) {                    // round-half-up (x / h in-loop path)
  u32 u = __builtin_bit_cast(u32, f);
  return (u16)((u + 0x8000u) >> 16);
}
DEVI u32 pkbf(float a, float b) {            // pack 2 bf16 into one dword
  u32 ua = __builtin_bit_cast(u32, a) + 0x8000u;
  u32 ub = __builtin_bit_cast(u32, b) + 0x8000u;
  return (ua >> 16) | (ub & 0xffff0000u);
}
// B-frag kt from tanh'd acc tiles: elements 0-3 = tile kt, 4-7 = tile kt+2
DEVI s16x8 packfrag(const f32x4& a, const f32x4& b) {
  u32x4 p;
  p[0] = pkbf(a[0], a[1]); p[1] = pkbf(a[2], a[3]);
  p[2] = pkbf(b[0], b[1]); p[3] = pkbf(b[2], b[3]);
  return __builtin_bit_cast(s16x8, p);
}
DEVI float tanhfast(float x) {               // 5 instrs with raw exp2
  float e = EXP2(x * -2.8853900817779268f);
  float r = __builtin_amdgcn_rcpf(1.0f + e);
  return __builtin_fmaf(2.0f, r, -1.0f);
}
DEVI f32x4 tanh4(const f32x4& v) {
  f32x4 r;
  r[0] = tanhfast(v[0]); r[1] = tanhfast(v[1]);
  r[2] = tanhfast(v[2]); r[3] = tanhfast(v[3]);
  return r;
}
DEVI f32x4 MFMA(s16x8 a, s16x8 b, f32x4 c) {
  return __builtin_amdgcn_mfma_f32_16x16x32_bf16(a, b, c, 0, 0, 0);
}
DEVI s16x8 ldrow8(const float* p) {          // 8 contiguous fp32 -> bf16 A-frag
  const f32x4 a = ((const f32x4*)p)[0];
  const f32x4 b = ((const f32x4*)p)[1];
  s16x8 r;
  r[0] = (short)f2bf(a[0]); r[1] = (short)f2bf(a[1]);
  r[2] = (short)f2bf(a[2]); r[3] = (short)f2bf(a[3]);
  r[4] = (short)f2bf(b[0]); r[5] = (short)f2bf(b[1]);
  r[6] = (short)f2bf(b[2]); r[7] = (short)f2bf(b[3]);
  return r;
}

// 3 waves/block; wave w owns layer w FULLY (R8-proven math/layout/dbuf protocol).
// NEW: chunked pipeline — each epoch processes K_=8 consecutive timesteps per
// wave (own recurrence register-resident, no sync within chunk); the handoff
// carries whole chunks. Barriers drop 133 -> 18; the ~1800cy/epoch floor is
// amortized over 8 steps. Wave0 streams x from global with one-chunk-ahead
// register prefetch (issued at epoch top, consumed at epoch end).
// hf is never read before written (c>=0 guards) => no zero-init needed.
// Arithmetic path bit-identical to R9/R10/R11 => absmax must be 5.859375e-3.
__global__ __launch_bounds__(192, 1) void rnn_ck(
    const float* __restrict__ x,
    const float* __restrict__ Wih0, const float* __restrict__ Whh0,
    const float* __restrict__ bih0, const float* __restrict__ bhh0,
    const float* __restrict__ Wih1, const float* __restrict__ Whh1,
    const float* __restrict__ bih1, const float* __restrict__ bhh1,
    const float* __restrict__ Wih2, const float* __restrict__ Whh2,
    const float* __restrict__ bih2, const float* __restrict__ bhh2,
    const float* __restrict__ fc1w, const float* __restrict__ fc1b,
    const float* __restrict__ fc2w, const float* __restrict__ fc2b,
    float* __restrict__ out)
{
  // [par][layer01][k][frag][lane] = 65536 B (R10 proved 64KiB static works).
  __shared__ __align__(16) u32x4 hf[2][2][K_][2][64];

  const int tid  = threadIdx.x;
  const int w    = tid >> 6;        // wave id = layer id
  const int lane = tid & 63;
  const int g    = lane >> 4;
  const int m    = lane & 15;
  const int b0   = blockIdx.x * BPB;

  f32x4 z4; z4[0] = 0.f; z4[1] = 0.f; z4[2] = 0.f; z4[3] = 0.f;

  // ---- per-wave (per-layer) weights, all register-resident (R8-verbatim) ----
  s16x8 Ax[4], Ai[4][2], Ah[4][2];
  f32x4 bc[4];
  {
    const float* Wi = Wih1; const float* Wh = Whh0;
    const float* bi = bih0; const float* bh = bhh0;
    if (w == 1)      { Wi = Wih1; Wh = Whh1; bi = bih1; bh = bhh1; }
    else if (w == 2) { Wi = Wih2; Wh = Whh2; bi = bih2; bh = bhh2; }
    #pragma unroll
    for (int n = 0; n < 4; n++) {
      const int Lr = 32 * (n & 1) + 8 * (m >> 2) + 4 * (n >> 1) + (m & 3);
      if (w == 0) {                      // input side 64x14, zero-pad K to 32
        s16x8 r;
        #pragma unroll
        for (int j2 = 0; j2 < 8; j2++) {
          const int kk = 8 * g + j2;
          r[j2] = (kk < F_) ? (short)f2bf(Wih0[Lr * F_ + kk]) : (short)0;
        }
        Ax[n] = r;
        Ai[n][0] = r; Ai[n][1] = r;      // dead in wave0
      } else {
        #pragma unroll
        for (int kt = 0; kt < 2; kt++)
          Ai[n][kt] = ldrow8(Wi + Lr * H_ + 32 * kt + 8 * g);
        Ax[n] = Ai[n][0];                // dead in waves 1/2
      }
      #pragma unroll
      for (int kt = 0; kt < 2; kt++)
        Ah[n][kt] = ldrow8(Wh + Lr * H_ + 32 * kt + 8 * g);
      const int Lb = 32 * (n & 1) + 8 * g + 4 * (n >> 1);
      bc[n] = *(const f32x4*)(bi + Lb) + *(const f32x4*)(bh + Lb);
    }
  }

  // ---- hh-state frags (own layer), zero init (h(-1)=0 in REGISTERS) ----
  s16x8 F[2];
  {
    s16x8 z;
    #pragma unroll
    for (int i = 0; i < 8; i++) z[i] = 0;
    F[0] = z; F[1] = z;
  }
  f32x4 h2v[4];
  #pragma unroll
  for (int n = 0; n < 4; n++) h2v[n] = z4;

  // ---- wave-0 x pipeline: chunk-granular register prefetch ----
  const float* xrow = x + (size_t)(b0 + m) * T_ * F_;
  auto ldraw = [&](int t, f32x4& ra, f32x4& rb) {    // R8-proven float2 loads
    const float* p = xrow + t * F_;
    if (g == 0) {
      f32x2 p0 = *(const f32x2*)(p),     p1 = *(const f32x2*)(p + 2);
      f32x2 p2 = *(const f32x2*)(p + 4), p3 = *(const f32x2*)(p + 6);
      ra[0] = p0[0]; ra[1] = p0[1]; ra[2] = p1[0]; ra[3] = p1[1];
      rb[0] = p2[0]; rb[1] = p2[1]; rb[2] = p3[0]; rb[3] = p3[1];
    } else if (g == 1) {
      f32x2 p4 = *(const f32x2*)(p + 8), p5 = *(const f32x2*)(p + 10);
      f32x2 p6 = *(const f32x2*)(p + 12);
      ra[0] = p4[0]; ra[1] = p4[1]; ra[2] = p5[0]; ra[3] = p5[1];
      rb[0] = p6[0]; rb[1] = p6[1]; rb[2] = 0.f;   rb[3] = 0.f;
    } else {
      ra = z4; rb = z4;
    }
  };
  auto cvtraw = [&](const f32x4& ra, const f32x4& rb) -> s16x8 {
    s16x8 r;
    r[0] = (short)f2bfF(ra[0]); r[1] = (short)f2bfF(ra[1]);
    r[2] = (short)f2bfF(ra[2]); r[3] = (short)f2bfF(ra[3]);
    r[4] = (short)f2bfF(rb[0]); r[5] = (short)f2bfF(rb[1]);
    r[6] = (short)f2bfF(rb[2]); r[7] = (short)f2bfF(rb[3]);
    return r;
  };

  s16x8 cur[K_];              // current chunk's x frags (wave0)
  f32x4 nra[K_], nrb[K_];     // next chunk's raw x (in flight across the epoch)
  if (w == 0) {
    #pragma unroll
    for (int k = 0; k < K_; k++) { ldraw(k, nra[k], nrb[k]); }
    #pragma unroll
    for (int k = 0; k < K_; k++) cur[k] = cvtraw(nra[k], nrb[k]);
  }

  // ---- chunked pipelined loop: epoch e, wave w does chunk c = e - w ----
  #pragma unroll 1
  for (int e = 0; e < NCH + 2; e++) {
    const int c  = e - w;
    const int wb = e & 1, rb = wb ^ 1;

    if (w == 0) {                        // issue next chunk's loads NOW
      int cn = e + 1; if (cn > NCH - 1) cn = NCH - 1;
      #pragma unroll
      for (int k = 0; k < K_; k++) ldraw(cn * K_ + k, nra[k], nrb[k]);
    }

    if (c >= 0 && c < NCH) {             // wave-uniform
      #pragma unroll
      for (int k = 0; k < K_; k++) {
        s16x8 Fp0, Fp1;
        if (w == 0) {
          Fp0 = cur[k]; Fp1 = cur[k];
        } else if (w == 1) {
          Fp0 = __builtin_bit_cast(s16x8, hf[rb][0][k][0][lane]);
          Fp1 = __builtin_bit_cast(s16x8, hf[rb][0][k][1][lane]);
        } else {
          Fp0 = __builtin_bit_cast(s16x8, hf[rb][1][k][0][lane]);
          Fp1 = __builtin_bit_cast(s16x8, hf[rb][1][k][1][lane]);
        }
        f32x4 p[4], q[4], hv[4];
        // parallel trees (R9-proven): p = bc + Ah*F ; q = Ai*Fp (zero-C)
        #pragma unroll
        for (int n = 0; n < 4; n++) p[n] = MFMA(Ah[n][0], F[0], bc[n]);
        #pragma unroll
        for (int n = 0; n < 4; n++) p[n] = MFMA(Ah[n][1], F[1], p[n]);
        if (w == 0) {
          #pragma unroll
          for (int n = 0; n < 4; n++) q[n] = MFMA(Ax[n], Fp0, z4);
        } else {
          #pragma unroll
          for (int n = 0; n < 4; n++) q[n] = MFMA(Ai[n][0], Fp0, z4);
          #pragma unroll
          for (int n = 0; n < 4; n++) q[n] = MFMA(Ai[n][1], Fp1, q[n]);
        }
        #pragma unroll
        for (int n = 0; n < 4; n++) hv[n] = tanh4(p[n] + q[n]);
        F[0] = packfrag(hv[0], hv[2]);
        F[1] = packfrag(hv[1], hv[3]);
        if (w < 2) {
          hf[wb][w][k][0][lane] = __builtin_bit_cast(u32x4, F[0]);
          hf[wb][w][k][1][lane] = __builtin_bit_cast(u32x4, F[1]);
        } else if (c == NCH - 1 && k == K_ - 1) {
          #pragma unroll
          for (int n = 0; n < 4; n++) h2v[n] = hv[n];   // fp32 h2 for head
        }
      }
    }

    if (w == 0) {                        // convert next chunk (loads now done)
      #pragma unroll
      for (int k = 0; k < K_; k++) cur[k] = cvtraw(nra[k], nrb[k]);
    }
    __syncthreads();   // single chunk-granular barrier (R8 dbuf protocol)
  }

  // ---- FC head: h2l overlays dead hf; wave 2 un-permutes, wave 0 computes ----
  float (*h2l)[68] = (float (*)[68])&hf[0][0][0][0][0];
  if (w == 2) {
    #pragma unroll
    for (int n = 0; n < 4; n++) {
      const int Lb = 32 * (n & 1) + 8 * g + 4 * (n >> 1);
      *(f32x4*)&h2l[m][Lb] = h2v[n];
    }
  }
  __syncthreads();

  if (w == 0) {
    float hr[64];
    #pragma unroll
    for (int q = 0; q < 16; q++) {
      f32x4 v = *(const f32x4*)&h2l[m][4 * q];
      hr[4 * q + 0] = v[0]; hr[4 * q + 1] = v[1];
      hr[4 * q + 2] = v[2]; hr[4 * q + 3] = v[3];
    }
    float acc2 = 0.f;
    #pragma unroll
    for (int jj = 0; jj < 8; jj++) {
      const int jf = 8 * g + jj;
      float s = fc1b[jf];
      const f32x4* wp = (const f32x4*)(fc1w + jf * H_);
      #pragma unroll
      for (int kq = 0; kq < 16; kq++) {
        f32x4 wv = wp[kq];
        s += hr[4 * kq + 0] * wv[0] + hr[4 * kq + 1] * wv[1]
           + hr[4 * kq + 2] * wv[2] + hr[4 * kq + 3] * wv[3];
      }
      s = fmaxf(s, 0.f);
      acc2 += s * fc2w[jf];
    }
    acc2 += __shfl_xor(acc2, 16, 64);
    acc2 += __shfl_xor(acc2, 32, 64);
    if (lane < 16) out[b0 + m] = acc2 + fc2b[0];
  }
}

extern "C" void kernel_launch(void* const* d_in, const int* in_sizes, int n_in,
                              void* d_out, int out_size, void* d_ws, size_t ws_size,
                              hipStream_t stream) {
  const float* x    = (const float*)d_in[0];
  const float* Wih0 = (const float*)d_in[1];
  const float* Whh0 = (const float*)d_in[2];
  const float* bih0 = (const float*)d_in[3];
  const float* bhh0 = (const float*)d_in[4];
  const float* Wih1 = (const float*)d_in[5];
  const float* Whh1 = (const float*)d_in[6];
  const float* bih1 = (const float*)d_in[7];
  const float* bhh1 = (const float*)d_in[8];
  const float* Wih2 = (const float*)d_in[9];
  const float* Whh2 = (const float*)d_in[10];
  const float* bih2 = (const float*)d_in[11];
  const float* bhh2 = (const float*)d_in[12];
  const float* fc1w = (const float*)d_in[13];
  const float* fc1b = (const float*)d_in[14];
  const float* fc2w = (const float*)d_in[15];
  const float* fc2b = (const float*)d_in[16];

  rnn_ck<<<dim3(4096 / BPB), dim3(192), 0, stream>>>(
      x, Wih0, Whh0, bih0, bhh0, Wih1, Whh1, bih1, bhh1,
      Wih2, Whh2, bih2, bhh2, fc1w, fc1b, fc2w, fc2b, (float*)d_out);
}